// Round 3
// baseline (88.393 us; speedup 1.0000x reference)
//
#include <hip/hip_runtime.h>
#include <hip/hip_bf16.h>

// 3x3 VALID conv via bf16 MFMA implicit GEMM.
// x: (64,224,224) fp32, w: (128,64,3,3) fp32, out: (128,222,222) fp32.
//
// R12: two launches instead of three. Evidence: R11 (barrier-free conv,
// 2x occupancy) == R9 total within noise -> conv is not the dominant cost;
// residual after the fixed ~43.5us harness poison-fill is ~44.5us vs ~12us
// of modeled kernel work, pointing at per-dispatch drain/launch gaps and
// serialized independent prep work.
//   1) prep_kernel: weight transform (288 units) + x transpose (904 units)
//      in ONE flat 1192-block grid -- they write disjoint buffers, so they
//      now run concurrently and one launch gap disappears.
//   2) conv: R11's barrier-free A-from-global design + ni=2 register tile
//      (each wave computes 2 output rows, each A-fragment feeds 2 MFMAs) ->
//      halves L1 A-traffic per MFMA (the modeled conv floor). 128-thread
//      blocks, tile 64co x 4oh x 32ow, grid 784 (even block/CU spread),
//      LDS 29,376 B, single __syncthreads after xs staging.
// A: m=lane&31, k=(lane>>5)*8+j. B: n=lane&31. D: col=lane&31,
// row=(reg&3)+8*(reg>>2)+4*(lane>>5)  [m74/m101-verified].

#define H_IN   224
#define W_IN   224
#define C_OUT  128
#define H_OUT  222
#define W_OUT  222
#define XP     226   // padded spatial extent of xt
#define CPAD   72    // padded c stride in conv x-LDS (144B = 16B*9, bank-floor)
#define TW     68    // padded w stride in transpose LDS

#define PREP_W_UNITS 288    // 288*256 = 73,728 weight elements
#define PREP_UNITS   1192   // 288 + 226 rows x 4 col-strips

typedef __attribute__((ext_vector_type(8)))  short bf16x8;
typedef __attribute__((ext_vector_type(16))) float f32x16;

static __device__ __forceinline__ unsigned short f2bs(float f) {
    union { __hip_bfloat16 h; unsigned short u; } cv;
    cv.h = __float2bfloat16(f);
    return cv.u;
}

// wt layout: [ij][kstep(=c>>3)][co][c&7] -> A-fragment reads lane-contiguous.
__global__ __launch_bounds__(256)
void prep_kernel(const float* __restrict__ x, const float* __restrict__ w,
                 __hip_bfloat16* __restrict__ xt, __hip_bfloat16* __restrict__ wt)
{
    __shared__ __align__(16) unsigned short tile[64 * TW];   // [c][w_local]
    const int u = blockIdx.x;
    const int t = threadIdx.x;

    if (u < PREP_W_UNITS) {
        // ---- weight transform: 1 element per thread ----
        int idx = u * 256 + t;                  // 0..73,727
        int ij  = idx >> 13;
        int rem = idx & 8191;
        int co  = rem >> 6;
        int c   = rem & 63;
        wt[((ij * 8 + (c >> 3)) * 128 + co) * 8 + (c & 7)] =
            __float2bfloat16(w[(co * 64 + c) * 9 + ij]);
        return;
    }

    // ---- x transpose: one (row h, 64-col strip) per block ----
    const int ux = u - PREP_W_UNITS;            // 0..903
    const int h  = ux >> 2;                     // 0..225
    const int w0 = (ux & 3) * 64;               // 0,64,128,192

    // Phase 1: coalesced float4 reads along w; zeros for padded h/w.
    {
        const int wq = (t & 15) * 4;            // 0..60 (lanes contiguous in w)
        const int c0 = t >> 4;                  // 0..15
        #pragma unroll
        for (int p = 0; p < 4; ++p) {
            const int c  = c0 + p * 16;
            const int wg = w0 + wq;
            float4 v = make_float4(0.f, 0.f, 0.f, 0.f);
            if (h < H_IN && wg < W_IN)          // W_IN%4==0 -> all-or-nothing
                v = *(const float4*)(x + ((size_t)c * H_IN + h) * W_IN + wg);
            ushort4 b;
            b.x = f2bs(v.x); b.y = f2bs(v.y); b.z = f2bs(v.z); b.w = f2bs(v.w);
            *(ushort4*)(tile + c * TW + wq) = b;
        }
    }
    __syncthreads();

    // Phase 2: gather 16 c per thread from LDS, contiguous 16B/lane stores.
    {
        const int wl = t >> 2;                  // 0..63
        const int cq = (t & 3) * 16;            // 0,16,32,48
        const int wg = w0 + wl;
        if (wg < XP) {
            alignas(16) unsigned short r[16];
            #pragma unroll
            for (int k = 0; k < 16; ++k)
                r[k] = tile[(cq + k) * TW + wl];
            float4* d = (float4*)((unsigned short*)xt + ((size_t)h * XP + wg) * 64 + cq);
            d[0] = ((const float4*)r)[0];
            d[1] = ((const float4*)r)[1];
        }
    }
}

__global__ __launch_bounds__(128, 2)
void conv_mfma_kernel(const __hip_bfloat16* __restrict__ xt,
                      const __hip_bfloat16* __restrict__ wt,
                      float* __restrict__ out)
{
    __shared__ __hip_bfloat16 xs[6 * 34 * CPAD];   // [row][wc][c]  29,376 B
    const int ow0 = blockIdx.x * 32;
    const int oh0 = blockIdx.y * 4;
    const int co0 = blockIdx.z * 64;
    const int tid = threadIdx.x;

    // Stage x tile: rows oh0..oh0+5, cols ow0..ow0+33, all 64 c (bf16).
    for (int q = tid; q < 6 * 34 * 8; q += 128) {
        int sub = q & 7;
        int pix = q >> 3;
        int row = pix / 34;
        int wc  = pix - row * 34;
        *(float4*)(xs + (row * 34 + wc) * CPAD + sub * 8) =
            *(const float4*)(xt + ((oh0 + row) * XP + (ow0 + wc)) * 64 + sub * 8);
    }
    __syncthreads();   // the ONLY barrier: xs is read-only from here on

    const int wave = tid >> 6;      // 0..1
    const int lane = tid & 63;
    const int n    = lane & 31;     // A: co offset; B: ow offset; D: col
    const int h    = lane >> 5;     // k-half selector
    const int r0   = wave * 2;      // this wave's 2 output rows

    f32x16 acc[2][2] = {};          // [mi][ni]

    #pragma unroll
    for (int p = 0; p < 9; ++p) {   // tap index = i*3 + jj
        const int i  = p / 3;
        const int jj = p - i * 3;
        #pragma unroll
        for (int t = 0; t < 4; ++t) {
            // A-fragments straight from global (L1/L2-resident, 1KB/wave
            // coalesced); each feeds 2 MFMAs via the ni=2 tile.
            bf16x8 afr[2], bfr[2];
            #pragma unroll
            for (int mi = 0; mi < 2; ++mi)
                afr[mi] = *(const bf16x8*)(wt +
                    (size_t)(((p * 8 + t * 2 + h) * 128 + co0 + mi * 32 + n) * 8));
            #pragma unroll
            for (int ni = 0; ni < 2; ++ni)
                bfr[ni] = *(const bf16x8*)(xs +
                    ((i + r0 + ni) * 34 + n + jj) * CPAD + t * 16 + h * 8);
            #pragma unroll
            for (int mi = 0; mi < 2; ++mi)
                #pragma unroll
                for (int ni = 0; ni < 2; ++ni)
                    acc[mi][ni] = __builtin_amdgcn_mfma_f32_32x32x16_bf16(
                        afr[mi], bfr[ni], acc[mi][ni], 0, 0, 0);
        }
    }

    // Epilogue: lanes 0..31 = 32 consecutive ow -> 128B full-line stores.
    #pragma unroll
    for (int mi = 0; mi < 2; ++mi) {
        #pragma unroll
        for (int ni = 0; ni < 2; ++ni) {
            const int oh = oh0 + r0 + ni;
            const int ow = ow0 + n;
            if (oh < H_OUT && ow < W_OUT) {
                #pragma unroll
                for (int r = 0; r < 16; ++r) {
                    int co = co0 + mi * 32 + (r & 3) + 8 * (r >> 2) + 4 * h;
                    out[(size_t)co * (H_OUT * W_OUT) + oh * W_OUT + ow] = acc[mi][ni][r];
                }
            }
        }
    }
}

extern "C" void kernel_launch(void* const* d_in, const int* in_sizes, int n_in,
                              void* d_out, int out_size, void* d_ws, size_t ws_size,
                              hipStream_t stream)
{
    const float* x = (const float*)d_in[0];
    const float* w = (const float*)d_in[1];
    float* out     = (float*)d_out;

    __hip_bfloat16* xt = (__hip_bfloat16*)d_ws;                      // 226*226*64*2 B
    __hip_bfloat16* wt = (__hip_bfloat16*)((char*)d_ws + (size_t)XP * XP * 64 * 2);

    prep_kernel<<<PREP_UNITS, 256, 0, stream>>>(x, w, xt, wt);
    conv_mfma_kernel<<<dim3(7, 56, 2), 128, 0, stream>>>(xt, wt, out);
}